// Round 1
// baseline (617.067 us; speedup 1.0000x reference)
//
#include <hip/hip_runtime.h>
#include <hip/hip_bf16.h>

#define INF 128
#define OUTF 64
#define ALPHA 0.2f
#define EPSV 1e-6f

// ---------------------------------------------------------------------------
// Kernel 1: Wh = h @ W_fc^T, fused s1 = Wh . a_src, s2 = Wh . a_dst
// One thread per (b,n) row. h row lives in 128 VGPRs; W_fc / W_attn are
// wave-uniform -> compiler emits scalar (s_load) reads, FMAs are v,s,v.
// ---------------------------------------------------------------------------
__global__ __launch_bounds__(256, 2)
void k_fc(const float* __restrict__ h, const float* __restrict__ Wfc,
          const float* __restrict__ Wattn, float* __restrict__ Wh,
          float* __restrict__ s1, float* __restrict__ s2, int BN)
{
    int row = blockIdx.x * 256 + threadIdx.x;
    if (row >= BN) return;

    float4 hreg[32];
    const float4* hp = (const float4*)(h + (size_t)row * INF);
#pragma unroll
    for (int i = 0; i < 32; ++i) hreg[i] = hp[i];

    float acc_s1 = 0.f, acc_s2 = 0.f;
    float* whp = Wh + (size_t)row * OUTF;

#pragma unroll 1
    for (int f4 = 0; f4 < OUTF / 4; ++f4) {
        float out4[4];
#pragma unroll
        for (int j = 0; j < 4; ++j) {
            int f = f4 * 4 + j;
            const float4* wp = (const float4*)(Wfc + (size_t)f * INF);
            float acc = 0.f;
#pragma unroll
            for (int i = 0; i < 32; ++i) {
                float4 w = wp[i];
                float4 hv = hreg[i];
                acc += w.x * hv.x + w.y * hv.y + w.z * hv.z + w.w * hv.w;
            }
            out4[j] = acc;
            acc_s1 += acc * Wattn[f];
            acc_s2 += acc * Wattn[OUTF + f];
        }
        *(float4*)(whp + f4 * 4) = make_float4(out4[0], out4[1], out4[2], out4[3]);
    }
    s1[row] = acc_s1;
    s2[row] = acc_s2;
}

// ---------------------------------------------------------------------------
// Kernel 2: per-edge scatter. One wave per edge, inner loop over batch.
//   e_exp = exp(leaky_relu(s1[src] + s2[dst]))
//   A[dst, f]   += e_exp * Wh[src, f]     (lane f, 64 lanes)
//   norm[dst]   += e_exp                  (lane 0)
// A is accumulated UNnormalized; division by (norm+eps) happens in k_final.
// ---------------------------------------------------------------------------
__global__ __launch_bounds__(256, 8)
void k_edge(const int* __restrict__ e_src, const int* __restrict__ e_dst,
            const float* __restrict__ Wh, const float* __restrict__ s1,
            const float* __restrict__ s2, float* __restrict__ norm,
            float* __restrict__ outacc, int E, int N)
{
    int wave = (blockIdx.x * 256 + threadIdx.x) >> 6;
    int lane = threadIdx.x & 63;
    if (wave >= E) return;

    int s = e_src[wave];
    int d = e_dst[wave];
    // clamp for safety (also guards against index-dtype surprises)
    s = min(max(s, 0), N - 1);
    d = min(max(d, 0), N - 1);

#pragma unroll
    for (int b = 0; b < 2; ++b) {
        int sb = b * N + s;
        int db = b * N + d;
        float ev = s1[sb] + s2[db];
        ev = ev > 0.f ? ev : ALPHA * ev;
        float eexp = __expf(ev);
        float w = Wh[(size_t)sb * OUTF + lane];
        atomicAdd(outacc + (size_t)db * OUTF + lane, w * eexp);
        if (lane == 0) atomicAdd(norm + db, eexp);
    }
}

// ---------------------------------------------------------------------------
// Kernel 3: out = elu(A / (norm + eps)), in place on d_out, float4 per thread.
// ---------------------------------------------------------------------------
__global__ __launch_bounds__(256)
void k_final(float* __restrict__ out, const float* __restrict__ norm, int total4)
{
    int i = blockIdx.x * 256 + threadIdx.x;
    if (i >= total4) return;
    float4 v = ((const float4*)out)[i];
    float nrm = norm[i >> 4];          // 16 float4 chunks per 64-float node row
    float inv = 1.f / (nrm + EPSV);
    v.x *= inv; v.y *= inv; v.z *= inv; v.w *= inv;
    v.x = v.x > 0.f ? v.x : expm1f(v.x);
    v.y = v.y > 0.f ? v.y : expm1f(v.y);
    v.z = v.z > 0.f ? v.z : expm1f(v.z);
    v.w = v.w > 0.f ? v.w : expm1f(v.w);
    ((float4*)out)[i] = v;
}

extern "C" void kernel_launch(void* const* d_in, const int* in_sizes, int n_in,
                              void* d_out, int out_size, void* d_ws, size_t ws_size,
                              hipStream_t stream)
{
    const float* h     = (const float*)d_in[0];
    const int*   ei    = (const int*)d_in[1];
    const float* Wfc   = (const float*)d_in[2];
    const float* Wattn = (const float*)d_in[3];
    float* out = (float*)d_out;

    int BN = in_sizes[0] / INF;     // B*N = 100000
    int N  = BN / 2;                // 50000
    int E  = in_sizes[1] / 2;       // 800000

    // workspace layout (floats): Wh[BN*64] | s1[BN] | s2[BN] | norm[BN]
    float* Wh   = (float*)d_ws;
    float* s1   = Wh + (size_t)BN * OUTF;
    float* s2   = s1 + BN;
    float* norm = s2 + BN;

    hipMemsetAsync(d_out, 0, (size_t)out_size * sizeof(float), stream);
    hipMemsetAsync(norm, 0, (size_t)BN * sizeof(float), stream);

    k_fc<<<(BN + 255) / 256, 256, 0, stream>>>(h, Wfc, Wattn, Wh, s1, s2, BN);
    k_edge<<<(E + 3) / 4, 256, 0, stream>>>(ei, ei + E, Wh, s1, s2, norm, out, E, N);
    k_final<<<(BN * (OUTF / 4) + 255) / 256, 256, 0, stream>>>(out, norm, BN * (OUTF / 4));
}

// Round 2
// 527.084 us; speedup vs baseline: 1.1707x; 1.1707x over previous
//
#include <hip/hip_runtime.h>
#include <hip/hip_bf16.h>

#define INF 128
#define OUTF 64
#define ALPHA 0.2f
#define EPSV 1e-6f

// ---------------------------------------------------------------------------
// k_fc: Wh = h @ Wfc^T, fused s1 = Wh.a_src, s2 = Wh.a_dst.
// One wave per 16 rows; lane = output feature f. Lane f holds W_fc row f in
// VGPRs (128). h chunks are wave-uniform scalar loads -> v_fmac v,s,v.
// ---------------------------------------------------------------------------
__global__ __launch_bounds__(256)
void k_fc(const float* __restrict__ h, const float* __restrict__ Wfc,
          const float* __restrict__ Wattn, float* __restrict__ Wh,
          float* __restrict__ s1, float* __restrict__ s2, int BN)
{
    int lane = threadIdx.x & 63;
    int wave = __builtin_amdgcn_readfirstlane((int)(threadIdx.x >> 6));
    int wbase = blockIdx.x * 64 + wave * 16;   // first row of this wave
    if (wbase >= BN) return;

    // W row `lane` -> 128 VGPRs (32 KB total, L1/L2 resident after warmup)
    float4 wreg[32];
    const float4* wp = (const float4*)(Wfc + (size_t)lane * INF);
#pragma unroll
    for (int i = 0; i < 32; ++i) wreg[i] = wp[i];

    float aS = Wattn[lane];
    float aD = Wattn[OUTF + lane];

    const float* hw = h + (size_t)wbase * INF;
    int nrows = min(16, BN - wbase);

    for (int j = 0; j < 16; ++j) {
        if (j >= nrows) break;           // wave-uniform guard (last block only)
        float acc = 0.f;
        const float4* hj = (const float4*)(hw + (size_t)j * INF);
#pragma unroll
        for (int c = 0; c < 32; ++c) {
            float4 hv = hj[c];           // wave-uniform -> s_load_dwordx4
            float4 w = wreg[c];
            acc += hv.x * w.x + hv.y * w.y + hv.z * w.z + hv.w * w.w;
        }
        int row = wbase + j;
        Wh[(size_t)row * OUTF + lane] = acc;   // coalesced 256B store

        // butterfly-reduce s1/s2 across the 64 lanes
        float t1 = acc * aS, t2 = acc * aD;
#pragma unroll
        for (int off = 32; off >= 1; off >>= 1) {
            t1 += __shfl_xor(t1, off, 64);
            t2 += __shfl_xor(t2, off, 64);
        }
        if (lane == 0) { s1[row] = t1; s2[row] = t2; }
    }
}

// ---------------------------------------------------------------------------
// Sort-by-dst passes: histogram -> single-block scan -> scatter src ids.
// ---------------------------------------------------------------------------
__global__ __launch_bounds__(256)
void k_hist(const int* __restrict__ e_dst, int* __restrict__ deg, int E, int N)
{
    int e = blockIdx.x * 256 + threadIdx.x;
    if (e >= E) return;
    int d = e_dst[e];
    d = min(max(d, 0), N - 1);
    atomicAdd(deg + d, 1);
}

__global__ __launch_bounds__(1024)
void k_scan(const int* __restrict__ deg, int* __restrict__ rowptr,
            int* __restrict__ cursor, int N)
{
    __shared__ int sums[1024];
    int tid = threadIdx.x;
    int C = (N + 1023) / 1024;
    int lo = tid * C, hi = min(N, lo + C);

    int s = 0;
    for (int i = lo; i < hi; ++i) s += deg[i];
    sums[tid] = s;
    __syncthreads();
    // Hillis-Steele inclusive scan over 1024 partial sums
    for (int off = 1; off < 1024; off <<= 1) {
        int v = (tid >= off) ? sums[tid - off] : 0;
        __syncthreads();
        sums[tid] += v;
        __syncthreads();
    }
    int running = sums[tid] - s;   // exclusive prefix of this chunk
    for (int i = lo; i < hi; ++i) {
        rowptr[i] = running;
        cursor[i] = running;
        running += deg[i];
    }
    if (hi == N && lo < N) rowptr[N] = running;
    if (tid == 1023 && lo >= N) rowptr[N] = sums[1023];
}

__global__ __launch_bounds__(256)
void k_scatter(const int* __restrict__ e_src, const int* __restrict__ e_dst,
               int* __restrict__ cursor, int* __restrict__ ssrc, int E, int N)
{
    int e = blockIdx.x * 256 + threadIdx.x;
    if (e >= E) return;
    int d = e_dst[e];
    d = min(max(d, 0), N - 1);
    int p = atomicAdd(cursor + d, 1);
    int s = e_src[e];
    ssrc[p] = min(max(s, 0), N - 1);
}

// ---------------------------------------------------------------------------
// k_gather: one wave per dst node, lane = feature. Both batches per wave.
// No atomics; epilogue (normalize + ELU) fused. Writes out exactly once.
// ---------------------------------------------------------------------------
__global__ __launch_bounds__(256)
void k_gather(const int* __restrict__ rowptr, const int* __restrict__ ssrc,
              const float* __restrict__ Wh, const float* __restrict__ s1,
              const float* __restrict__ s2, float* __restrict__ out, int N)
{
    int lane = threadIdx.x & 63;
    int d = blockIdx.x * 4 + (threadIdx.x >> 6);
    if (d >= N) return;

    int beg = rowptr[d];
    int end = rowptr[d + 1];
    float s2d0 = s2[d];
    float s2d1 = s2[N + d];

    float acc0 = 0.f, acc1 = 0.f, n0 = 0.f, n1 = 0.f;

    int s = (beg < end) ? ssrc[beg] : 0;
    for (int i = beg; i < end; ++i) {
        int snext = (i + 1 < end) ? ssrc[i + 1] : 0;   // 1-deep src prefetch
        float e0 = s1[s] + s2d0;
        float e1 = s1[N + s] + s2d1;
        e0 = e0 > 0.f ? e0 : ALPHA * e0;
        e1 = e1 > 0.f ? e1 : ALPHA * e1;
        float x0 = __expf(e0);
        float x1 = __expf(e1);
        const float* w = Wh + (size_t)s * OUTF;
        acc0 += x0 * w[lane];                          // coalesced 256B gather
        acc1 += x1 * w[(size_t)N * OUTF + lane];
        n0 += x0; n1 += x1;
        s = snext;
    }

    float o0 = acc0 / (n0 + EPSV);
    float o1 = acc1 / (n1 + EPSV);
    o0 = o0 > 0.f ? o0 : expm1f(o0);
    o1 = o1 > 0.f ? o1 : expm1f(o1);
    out[(size_t)d * OUTF + lane] = o0;
    out[((size_t)N + d) * OUTF + lane] = o1;
}

extern "C" void kernel_launch(void* const* d_in, const int* in_sizes, int n_in,
                              void* d_out, int out_size, void* d_ws, size_t ws_size,
                              hipStream_t stream)
{
    const float* h     = (const float*)d_in[0];
    const int*   ei    = (const int*)d_in[1];
    const float* Wfc   = (const float*)d_in[2];
    const float* Wattn = (const float*)d_in[3];
    float* out = (float*)d_out;

    int BN = in_sizes[0] / INF;     // B*N = 100000
    int N  = BN / 2;                // 50000
    int E  = in_sizes[1] / 2;       // 800000

    // ws layout: Wh[BN*64] | s1[BN] | s2[BN] | deg[N] | rowptr[N+1] | cursor[N+1] | ssrc[E]
    float* Wh     = (float*)d_ws;
    float* s1     = Wh + (size_t)BN * OUTF;
    float* s2     = s1 + BN;
    int*   deg    = (int*)(s2 + BN);
    int*   rowptr = deg + N;
    int*   cursor = rowptr + N + 1;
    int*   ssrc   = cursor + N + 1;

    hipMemsetAsync(deg, 0, (size_t)N * sizeof(int), stream);

    k_fc<<<(BN + 63) / 64, 256, 0, stream>>>(h, Wfc, Wattn, Wh, s1, s2, BN);
    k_hist<<<(E + 255) / 256, 256, 0, stream>>>(ei + E, deg, E, N);
    k_scan<<<1, 1024, 0, stream>>>(deg, rowptr, cursor, N);
    k_scatter<<<(E + 255) / 256, 256, 0, stream>>>(ei, ei + E, cursor, ssrc, E, N);
    k_gather<<<(N + 3) / 4, 256, 0, stream>>>(rowptr, ssrc, Wh, s1, s2, out, N);
}

// Round 3
// 451.734 us; speedup vs baseline: 1.3660x; 1.1668x over previous
//
#include <hip/hip_runtime.h>
#include <hip/hip_bf16.h>

#define INF 128
#define OUTF 64
#define ALPHA 0.2f
#define EPSV 1e-6f

// ---------------------------------------------------------------------------
// k_fc: Wh = h @ Wfc^T, fused s1 = Wh.a_src, s2 = Wh.a_dst.
// Lane f holds W_fc row f in 128 VGPRs (forced resident via launch_bounds).
// h rows stream through LDS; compute reads are wave-uniform ds_read_b128
// broadcasts (conflict-free). 32 rows/block, 8 rows/wave.
// ---------------------------------------------------------------------------
__global__ __launch_bounds__(256, 2)
void k_fc(const float* __restrict__ h, const float* __restrict__ Wfc,
          const float* __restrict__ Wattn, float* __restrict__ Wh,
          float* __restrict__ s1, float* __restrict__ s2, int BN)
{
    __shared__ float4 hlds[32 * 32];          // 32 rows x 128 floats = 16 KB
    int t = threadIdx.x;
    int lane = t & 63;
    int wave = t >> 6;
    int rowbase = blockIdx.x * 32;
    if (rowbase >= BN) return;

    // W row `lane` -> 128 VGPRs (32 KB total; L2-resident across blocks)
    float4 wreg[32];
    const float4* wp = (const float4*)(Wfc + (size_t)lane * INF);
#pragma unroll
    for (int i = 0; i < 32; ++i) wreg[i] = wp[i];
    float aS = Wattn[lane];
    float aD = Wattn[OUTF + lane];

    // stage up to 32 h rows, coalesced float4
    const float4* hg = (const float4*)(h + (size_t)rowbase * INF);
    int avail4 = min(32 * 32, (BN - rowbase) * (INF / 4));
#pragma unroll
    for (int p = 0; p < 4; ++p) {
        int idx = p * 256 + t;
        if (idx < avail4) hlds[idx] = hg[idx];
    }
    __syncthreads();

#pragma unroll 1
    for (int j = 0; j < 8; ++j) {
        int r = wave * 8 + j;
        int row = rowbase + r;
        if (row >= BN) break;                  // wave-uniform guard
        const float4* hr = hlds + r * 32;
        float a0 = 0.f, a1 = 0.f, a2 = 0.f, a3 = 0.f;
#pragma unroll
        for (int c = 0; c < 32; c += 4) {
            float4 h0 = hr[c + 0], h1 = hr[c + 1], h2 = hr[c + 2], h3 = hr[c + 3];
            float4 w0 = wreg[c + 0], w1 = wreg[c + 1], w2 = wreg[c + 2], w3 = wreg[c + 3];
            a0 += h0.x * w0.x + h0.y * w0.y + h0.z * w0.z + h0.w * w0.w;
            a1 += h1.x * w1.x + h1.y * w1.y + h1.z * w1.z + h1.w * w1.w;
            a2 += h2.x * w2.x + h2.y * w2.y + h2.z * w2.z + h2.w * w2.w;
            a3 += h3.x * w3.x + h3.y * w3.y + h3.z * w3.z + h3.w * w3.w;
        }
        float acc = (a0 + a1) + (a2 + a3);
        Wh[(size_t)row * OUTF + lane] = acc;   // coalesced 256B store

        float t1 = acc * aS, t2 = acc * aD;
#pragma unroll
        for (int off = 32; off >= 1; off >>= 1) {
            t1 += __shfl_xor(t1, off, 64);
            t2 += __shfl_xor(t2, off, 64);
        }
        if (lane == 0) { s1[row] = t1; s2[row] = t2; }
    }
}

// ---------------------------------------------------------------------------
// Sort-by-dst passes: histogram -> single-block scan -> scatter src ids.
// ---------------------------------------------------------------------------
__global__ __launch_bounds__(256)
void k_hist(const int* __restrict__ e_dst, int* __restrict__ deg, int E, int N)
{
    int e = blockIdx.x * 256 + threadIdx.x;
    if (e >= E) return;
    int d = e_dst[e];
    d = min(max(d, 0), N - 1);
    atomicAdd(deg + d, 1);
}

__global__ __launch_bounds__(1024)
void k_scan(const int* __restrict__ deg, int* __restrict__ rowptr,
            int* __restrict__ cursor, int N)
{
    __shared__ int sums[1024];
    int tid = threadIdx.x;
    int C = (N + 1023) / 1024;
    int lo = tid * C, hi = min(N, lo + C);

    int s = 0;
    for (int i = lo; i < hi; ++i) s += deg[i];
    sums[tid] = s;
    __syncthreads();
    for (int off = 1; off < 1024; off <<= 1) {
        int v = (tid >= off) ? sums[tid - off] : 0;
        __syncthreads();
        sums[tid] += v;
        __syncthreads();
    }
    int running = sums[tid] - s;
    for (int i = lo; i < hi; ++i) {
        rowptr[i] = running;
        cursor[i] = running;
        running += deg[i];
    }
    if (hi == N && lo < N) rowptr[N] = running;
    if (tid == 1023 && lo >= N) rowptr[N] = sums[1023];
}

__global__ __launch_bounds__(256)
void k_scatter(const int* __restrict__ e_src, const int* __restrict__ e_dst,
               int* __restrict__ cursor, int* __restrict__ ssrc, int E, int N)
{
    int e = blockIdx.x * 256 + threadIdx.x;
    if (e >= E) return;
    int d = e_dst[e];
    d = min(max(d, 0), N - 1);
    int p = atomicAdd(cursor + d, 1);
    int s = e_src[e];
    ssrc[p] = min(max(s, 0), N - 1);
}

// ---------------------------------------------------------------------------
// k_gather: one wave per dst node, lane = feature. Both batches per wave.
// No atomics; epilogue (normalize + ELU) fused.
// ---------------------------------------------------------------------------
__global__ __launch_bounds__(256)
void k_gather(const int* __restrict__ rowptr, const int* __restrict__ ssrc,
              const float* __restrict__ Wh, const float* __restrict__ s1,
              const float* __restrict__ s2, float* __restrict__ out, int N)
{
    int lane = threadIdx.x & 63;
    int d = blockIdx.x * 4 + (threadIdx.x >> 6);
    if (d >= N) return;

    int beg = rowptr[d];
    int end = rowptr[d + 1];
    float s2d0 = s2[d];
    float s2d1 = s2[N + d];

    float acc0 = 0.f, acc1 = 0.f, n0 = 0.f, n1 = 0.f;

    int s = (beg < end) ? ssrc[beg] : 0;
    for (int i = beg; i < end; ++i) {
        int snext = (i + 1 < end) ? ssrc[i + 1] : 0;   // 1-deep src prefetch
        float e0 = s1[s] + s2d0;
        float e1 = s1[N + s] + s2d1;
        e0 = e0 > 0.f ? e0 : ALPHA * e0;
        e1 = e1 > 0.f ? e1 : ALPHA * e1;
        float x0 = __expf(e0);
        float x1 = __expf(e1);
        const float* w = Wh + (size_t)s * OUTF;
        acc0 += x0 * w[lane];
        acc1 += x1 * w[(size_t)N * OUTF + lane];
        n0 += x0; n1 += x1;
        s = snext;
    }

    float o0 = acc0 / (n0 + EPSV);
    float o1 = acc1 / (n1 + EPSV);
    o0 = o0 > 0.f ? o0 : expm1f(o0);
    o1 = o1 > 0.f ? o1 : expm1f(o1);
    out[(size_t)d * OUTF + lane] = o0;
    out[((size_t)N + d) * OUTF + lane] = o1;
}

extern "C" void kernel_launch(void* const* d_in, const int* in_sizes, int n_in,
                              void* d_out, int out_size, void* d_ws, size_t ws_size,
                              hipStream_t stream)
{
    const float* h     = (const float*)d_in[0];
    const int*   ei    = (const int*)d_in[1];
    const float* Wfc   = (const float*)d_in[2];
    const float* Wattn = (const float*)d_in[3];
    float* out = (float*)d_out;

    int BN = in_sizes[0] / INF;     // B*N = 100000
    int N  = BN / 2;                // 50000
    int E  = in_sizes[1] / 2;       // 800000

    // ws layout: Wh[BN*64] | s1[BN] | s2[BN] | deg[N] | rowptr[N+1] | cursor[N+1] | ssrc[E]
    float* Wh     = (float*)d_ws;
    float* s1     = Wh + (size_t)BN * OUTF;
    float* s2     = s1 + BN;
    int*   deg    = (int*)(s2 + BN);
    int*   rowptr = deg + N;
    int*   cursor = rowptr + N + 1;
    int*   ssrc   = cursor + N + 1;

    hipMemsetAsync(deg, 0, (size_t)N * sizeof(int), stream);

    k_fc<<<(BN + 31) / 32, 256, 0, stream>>>(h, Wfc, Wattn, Wh, s1, s2, BN);
    k_hist<<<(E + 255) / 256, 256, 0, stream>>>(ei + E, deg, E, N);
    k_scan<<<1, 1024, 0, stream>>>(deg, rowptr, cursor, N);
    k_scatter<<<(E + 255) / 256, 256, 0, stream>>>(ei, ei + E, cursor, ssrc, E, N);
    k_gather<<<(N + 3) / 4, 256, 0, stream>>>(rowptr, ssrc, Wh, s1, s2, out, N);
}

// Round 4
// 342.624 us; speedup vs baseline: 1.8010x; 1.3185x over previous
//
#include <hip/hip_runtime.h>
#include <hip/hip_bf16.h>

#define INF 128
#define OUTF 64
#define ALPHA 0.2f
#define EPSV 1e-6f

// ---------------------------------------------------------------------------
// k_fc: Wh = h @ Wfc^T, fused s1 = Wh.a_src, s2 = Wh.a_dst.
// Lane f holds W_fc row f in 128 VGPRs. h rows stream through LDS; compute
// reads are wave-uniform ds_read_b128 broadcasts. 32 rows/block, 8 rows/wave.
// ---------------------------------------------------------------------------
__global__ __launch_bounds__(256, 2)
void k_fc(const float* __restrict__ h, const float* __restrict__ Wfc,
          const float* __restrict__ Wattn, float* __restrict__ Wh,
          float* __restrict__ s1, float* __restrict__ s2, int BN)
{
    __shared__ float4 hlds[32 * 32];          // 32 rows x 128 floats = 16 KB
    int t = threadIdx.x;
    int lane = t & 63;
    int wave = t >> 6;
    int rowbase = blockIdx.x * 32;
    if (rowbase >= BN) return;

    float4 wreg[32];
    const float4* wp = (const float4*)(Wfc + (size_t)lane * INF);
#pragma unroll
    for (int i = 0; i < 32; ++i) wreg[i] = wp[i];
    float aS = Wattn[lane];
    float aD = Wattn[OUTF + lane];

    const float4* hg = (const float4*)(h + (size_t)rowbase * INF);
    int avail4 = min(32 * 32, (BN - rowbase) * (INF / 4));
#pragma unroll
    for (int p = 0; p < 4; ++p) {
        int idx = p * 256 + t;
        if (idx < avail4) hlds[idx] = hg[idx];
    }
    __syncthreads();

#pragma unroll 1
    for (int j = 0; j < 8; ++j) {
        int r = wave * 8 + j;
        int row = rowbase + r;
        if (row >= BN) break;                  // wave-uniform guard
        const float4* hr = hlds + r * 32;
        float a0 = 0.f, a1 = 0.f, a2 = 0.f, a3 = 0.f;
#pragma unroll
        for (int c = 0; c < 32; c += 4) {
            float4 h0 = hr[c + 0], h1 = hr[c + 1], h2 = hr[c + 2], h3 = hr[c + 3];
            float4 w0 = wreg[c + 0], w1 = wreg[c + 1], w2 = wreg[c + 2], w3 = wreg[c + 3];
            a0 += h0.x * w0.x + h0.y * w0.y + h0.z * w0.z + h0.w * w0.w;
            a1 += h1.x * w1.x + h1.y * w1.y + h1.z * w1.z + h1.w * w1.w;
            a2 += h2.x * w2.x + h2.y * w2.y + h2.z * w2.z + h2.w * w2.w;
            a3 += h3.x * w3.x + h3.y * w3.y + h3.z * w3.z + h3.w * w3.w;
        }
        float acc = (a0 + a1) + (a2 + a3);
        Wh[(size_t)row * OUTF + lane] = acc;

        float t1 = acc * aS, t2 = acc * aD;
#pragma unroll
        for (int off = 32; off >= 1; off >>= 1) {
            t1 += __shfl_xor(t1, off, 64);
            t2 += __shfl_xor(t2, off, 64);
        }
        if (lane == 0) { s1[row] = t1; s2[row] = t2; }
    }
}

// ---------------------------------------------------------------------------
// Histogram by dst.
// ---------------------------------------------------------------------------
__global__ __launch_bounds__(256)
void k_hist(const int* __restrict__ e_dst, int* __restrict__ deg, int E, int N)
{
    int e = blockIdx.x * 256 + threadIdx.x;
    if (e >= E) return;
    int d = e_dst[e];
    d = min(max(d, 0), N - 1);
    atomicAdd(deg + d, 1);
}

// ---------------------------------------------------------------------------
// 3-phase parallel exclusive scan over deg[N]  (2048 elems per block).
// ---------------------------------------------------------------------------
__global__ __launch_bounds__(256)
void k_scan_blk(const int* __restrict__ deg, int* __restrict__ part, int N)
{
    int t = threadIdx.x, lane = t & 63, wave = t >> 6;
    int base = blockIdx.x * 2048 + t * 8;
    int s = 0;
#pragma unroll
    for (int j = 0; j < 8; ++j) { int i = base + j; if (i < N) s += deg[i]; }
#pragma unroll
    for (int off = 32; off >= 1; off >>= 1) s += __shfl_xor(s, off, 64);
    __shared__ int ws[4];
    if (lane == 0) ws[wave] = s;
    __syncthreads();
    if (t == 0) part[blockIdx.x] = ws[0] + ws[1] + ws[2] + ws[3];
}

__global__ __launch_bounds__(64)
void k_scan_mid(int* __restrict__ part, int* __restrict__ rowptrN, int nblk)
{
    int t = threadIdx.x;
    int v = (t < nblk) ? part[t] : 0;
    int orig = v;
#pragma unroll
    for (int off = 1; off < 64; off <<= 1) {
        int u = __shfl_up(v, off, 64);
        if (t >= off) v += u;
    }
    if (t < nblk) part[t] = v - orig;        // exclusive block offsets
    if (t == 63) *rowptrN = v;               // grand total -> rowptr[N]
}

__global__ __launch_bounds__(256)
void k_scan_fin(const int* __restrict__ deg, const int* __restrict__ part,
                int* __restrict__ rowptr, int* __restrict__ cursor, int N)
{
    int t = threadIdx.x, lane = t & 63, wave = t >> 6;
    int base = blockIdx.x * 2048 + t * 8;
    int vals[8]; int s = 0;
#pragma unroll
    for (int j = 0; j < 8; ++j) {
        int i = base + j;
        vals[j] = (i < N) ? deg[i] : 0;
        s += vals[j];
    }
    int inc = s;                              // wave-inclusive scan of thread sums
#pragma unroll
    for (int off = 1; off < 64; off <<= 1) {
        int u = __shfl_up(inc, off, 64);
        if (lane >= off) inc += u;
    }
    __shared__ int wsum[4];
    if (lane == 63) wsum[wave] = inc;
    __syncthreads();
    int woff = 0;
#pragma unroll
    for (int w = 0; w < 4; ++w) if (w < wave) woff += wsum[w];
    int running = part[blockIdx.x] + woff + (inc - s);
#pragma unroll
    for (int j = 0; j < 8; ++j) {
        int i = base + j;
        if (i < N) { rowptr[i] = running; cursor[i] = running; }
        running += vals[j];
    }
}

// ---------------------------------------------------------------------------
// Scatter src ids into dst-sorted order.
// ---------------------------------------------------------------------------
__global__ __launch_bounds__(256)
void k_scatter(const int* __restrict__ e_src, const int* __restrict__ e_dst,
               int* __restrict__ cursor, int* __restrict__ ssrc, int E, int N)
{
    int e = blockIdx.x * 256 + threadIdx.x;
    if (e >= E) return;
    int d = e_dst[e];
    d = min(max(d, 0), N - 1);
    int p = atomicAdd(cursor + d, 1);
    int s = e_src[e];
    ssrc[p] = min(max(s, 0), N - 1);
}

// ---------------------------------------------------------------------------
// k_gather: one wave per dst node, lane = feature. Both batches per wave.
// ---------------------------------------------------------------------------
__global__ __launch_bounds__(256)
void k_gather(const int* __restrict__ rowptr, const int* __restrict__ ssrc,
              const float* __restrict__ Wh, const float* __restrict__ s1,
              const float* __restrict__ s2, float* __restrict__ out, int N)
{
    int lane = threadIdx.x & 63;
    int d = blockIdx.x * 4 + (threadIdx.x >> 6);
    if (d >= N) return;

    int beg = rowptr[d];
    int end = rowptr[d + 1];
    float s2d0 = s2[d];
    float s2d1 = s2[N + d];

    float acc0 = 0.f, acc1 = 0.f, n0 = 0.f, n1 = 0.f;

    int s = (beg < end) ? ssrc[beg] : 0;
    for (int i = beg; i < end; ++i) {
        int snext = (i + 1 < end) ? ssrc[i + 1] : 0;
        float e0 = s1[s] + s2d0;
        float e1 = s1[N + s] + s2d1;
        e0 = e0 > 0.f ? e0 : ALPHA * e0;
        e1 = e1 > 0.f ? e1 : ALPHA * e1;
        float x0 = __expf(e0);
        float x1 = __expf(e1);
        const float* w = Wh + (size_t)s * OUTF;
        acc0 += x0 * w[lane];
        acc1 += x1 * w[(size_t)N * OUTF + lane];
        n0 += x0; n1 += x1;
        s = snext;
    }

    float o0 = acc0 / (n0 + EPSV);
    float o1 = acc1 / (n1 + EPSV);
    o0 = o0 > 0.f ? o0 : expm1f(o0);
    o1 = o1 > 0.f ? o1 : expm1f(o1);
    out[(size_t)d * OUTF + lane] = o0;
    out[((size_t)N + d) * OUTF + lane] = o1;
}

extern "C" void kernel_launch(void* const* d_in, const int* in_sizes, int n_in,
                              void* d_out, int out_size, void* d_ws, size_t ws_size,
                              hipStream_t stream)
{
    const float* h     = (const float*)d_in[0];
    const int*   ei    = (const int*)d_in[1];
    const float* Wfc   = (const float*)d_in[2];
    const float* Wattn = (const float*)d_in[3];
    float* out = (float*)d_out;

    int BN = in_sizes[0] / INF;     // B*N = 100000
    int N  = BN / 2;                // 50000
    int E  = in_sizes[1] / 2;       // 800000

    // ws layout: Wh[BN*64] | s1[BN] | s2[BN] | deg[N] | rowptr[N+1] | cursor[N+1] | ssrc[E] | part[64]
    float* Wh     = (float*)d_ws;
    float* s1     = Wh + (size_t)BN * OUTF;
    float* s2     = s1 + BN;
    int*   deg    = (int*)(s2 + BN);
    int*   rowptr = deg + N;
    int*   cursor = rowptr + N + 1;
    int*   ssrc   = cursor + N + 1;
    int*   part   = ssrc + E;

    int nblk = (N + 2047) / 2048;   // 25 for N=50000 (<=64 supported)

    hipMemsetAsync(deg, 0, (size_t)N * sizeof(int), stream);

    k_fc<<<(BN + 31) / 32, 256, 0, stream>>>(h, Wfc, Wattn, Wh, s1, s2, BN);
    k_hist<<<(E + 255) / 256, 256, 0, stream>>>(ei + E, deg, E, N);
    k_scan_blk<<<nblk, 256, 0, stream>>>(deg, part, N);
    k_scan_mid<<<1, 64, 0, stream>>>(part, rowptr + N, nblk);
    k_scan_fin<<<nblk, 256, 0, stream>>>(deg, part, rowptr, cursor, N);
    k_scatter<<<(E + 255) / 256, 256, 0, stream>>>(ei, ei + E, cursor, ssrc, E, N);
    k_gather<<<(N + 3) / 4, 256, 0, stream>>>(rowptr, ssrc, Wh, s1, s2, out, N);
}

// Round 5
// 264.146 us; speedup vs baseline: 2.3361x; 1.2971x over previous
//
#include <hip/hip_runtime.h>
#include <hip/hip_bf16.h>

#define INF 128
#define OUTF 64
#define ALPHA 0.2f
#define EPSV 1e-6f

typedef __bf16 bf16x8 __attribute__((ext_vector_type(8)));
typedef float  f32x4  __attribute__((ext_vector_type(4)));

// ---------------------------------------------------------------------------
// k_fc (MFMA): Wh = h @ Wfc^T via 16x16x32 bf16 MFMA, 3-term bf16 split for
// near-fp32 accuracy. One wave per 16 rows. W lives in 32 B-fragments (hi+lo).
// s1 = Wh.a_src, s2 = Wh.a_dst fused in the epilogue from C-fragments.
// A layout: A[m=lane&15][k=(lane>>4)*8+j]; B: B[k=(lane>>4)*8+j][n=lane&15];
// C/D: col=lane&15, row=(lane>>4)*4+reg.  (learn_hip m89/m91 verified)
// ---------------------------------------------------------------------------
__global__ __launch_bounds__(256, 2)
void k_fc(const float* __restrict__ h, const float* __restrict__ Wfc,
          const float* __restrict__ Wattn, float* __restrict__ Wh,
          float* __restrict__ s1, float* __restrict__ s2, int BN)
{
    int lane = threadIdx.x & 63;
    int wv   = blockIdx.x * 4 + (threadIdx.x >> 6);
    int base = wv * 16;
    if (base >= BN) return;
    int q = lane & 15, quad = lane >> 4;

    // B fragments: Wfc[n][k], n = t*16+q, k = kb*32 + quad*8 + j
    bf16x8 bhi[16], blo[16];
#pragma unroll
    for (int kb = 0; kb < 4; ++kb) {
#pragma unroll
        for (int t = 0; t < 4; ++t) {
            const float* wp = Wfc + (size_t)(t * 16 + q) * INF + kb * 32 + quad * 8;
            float4 w0 = *(const float4*)wp;
            float4 w1 = *(const float4*)(wp + 4);
            float wv8[8] = {w0.x, w0.y, w0.z, w0.w, w1.x, w1.y, w1.z, w1.w};
            bf16x8 hi8, lo8;
#pragma unroll
            for (int j = 0; j < 8; ++j) {
                hi8[j] = (__bf16)wv8[j];
                lo8[j] = (__bf16)(wv8[j] - (float)hi8[j]);
            }
            bhi[kb * 4 + t] = hi8;
            blo[kb * 4 + t] = lo8;
        }
    }

    f32x4 acc[4];
#pragma unroll
    for (int t = 0; t < 4; ++t) acc[t] = (f32x4){0.f, 0.f, 0.f, 0.f};

    const float* hrow = h + (size_t)(base + q) * INF + quad * 8;
#pragma unroll
    for (int kb = 0; kb < 4; ++kb) {
        float4 h0 = *(const float4*)(hrow + kb * 32);
        float4 h1 = *(const float4*)(hrow + kb * 32 + 4);
        float hv8[8] = {h0.x, h0.y, h0.z, h0.w, h1.x, h1.y, h1.z, h1.w};
        bf16x8 ahi, alo;
#pragma unroll
        for (int j = 0; j < 8; ++j) {
            ahi[j] = (__bf16)hv8[j];
            alo[j] = (__bf16)(hv8[j] - (float)ahi[j]);
        }
#pragma unroll
        for (int t = 0; t < 4; ++t) {
            acc[t] = __builtin_amdgcn_mfma_f32_16x16x32_bf16(ahi, bhi[kb * 4 + t], acc[t], 0, 0, 0);
            acc[t] = __builtin_amdgcn_mfma_f32_16x16x32_bf16(ahi, blo[kb * 4 + t], acc[t], 0, 0, 0);
            acc[t] = __builtin_amdgcn_mfma_f32_16x16x32_bf16(alo, bhi[kb * 4 + t], acc[t], 0, 0, 0);
        }
    }

    // store Wh: row = base + quad*4 + r, col = t*16 + q
#pragma unroll
    for (int t = 0; t < 4; ++t)
#pragma unroll
        for (int r = 0; r < 4; ++r)
            Wh[(size_t)(base + quad * 4 + r) * OUTF + t * 16 + q] = acc[t][r];

    // fused s1/s2: dot over the 64 cols = in-lane over t + shfl over 16 q-lanes
    float aS[4], aD[4];
#pragma unroll
    for (int t = 0; t < 4; ++t) {
        aS[t] = Wattn[t * 16 + q];
        aD[t] = Wattn[OUTF + t * 16 + q];
    }
    float t1[4], t2[4];
#pragma unroll
    for (int r = 0; r < 4; ++r) {
        t1[r] = acc[0][r] * aS[0] + acc[1][r] * aS[1] + acc[2][r] * aS[2] + acc[3][r] * aS[3];
        t2[r] = acc[0][r] * aD[0] + acc[1][r] * aD[1] + acc[2][r] * aD[2] + acc[3][r] * aD[3];
    }
#pragma unroll
    for (int off = 1; off <= 8; off <<= 1) {
#pragma unroll
        for (int r = 0; r < 4; ++r) {
            t1[r] += __shfl_xor(t1[r], off, 64);
            t2[r] += __shfl_xor(t2[r], off, 64);
        }
    }
    if (q == 0) {
#pragma unroll
        for (int r = 0; r < 4; ++r) {
            s1[base + quad * 4 + r] = t1[r];
            s2[base + quad * 4 + r] = t2[r];
        }
    }
}

// ---------------------------------------------------------------------------
// Histogram by dst.
// ---------------------------------------------------------------------------
__global__ __launch_bounds__(256)
void k_hist(const int* __restrict__ e_dst, int* __restrict__ deg, int E, int N)
{
    int e = blockIdx.x * 256 + threadIdx.x;
    if (e >= E) return;
    int d = e_dst[e];
    d = min(max(d, 0), N - 1);
    atomicAdd(deg + d, 1);
}

// ---------------------------------------------------------------------------
// 3-phase parallel exclusive scan over deg[N]  (2048 elems per block).
// ---------------------------------------------------------------------------
__global__ __launch_bounds__(256)
void k_scan_blk(const int* __restrict__ deg, int* __restrict__ part, int N)
{
    int t = threadIdx.x, lane = t & 63, wave = t >> 6;
    int base = blockIdx.x * 2048 + t * 8;
    int s = 0;
#pragma unroll
    for (int j = 0; j < 8; ++j) { int i = base + j; if (i < N) s += deg[i]; }
#pragma unroll
    for (int off = 32; off >= 1; off >>= 1) s += __shfl_xor(s, off, 64);
    __shared__ int ws[4];
    if (lane == 0) ws[wave] = s;
    __syncthreads();
    if (t == 0) part[blockIdx.x] = ws[0] + ws[1] + ws[2] + ws[3];
}

__global__ __launch_bounds__(64)
void k_scan_mid(int* __restrict__ part, int* __restrict__ rowptrN, int nblk)
{
    int t = threadIdx.x;
    int v = (t < nblk) ? part[t] : 0;
    int orig = v;
#pragma unroll
    for (int off = 1; off < 64; off <<= 1) {
        int u = __shfl_up(v, off, 64);
        if (t >= off) v += u;
    }
    if (t < nblk) part[t] = v - orig;
    if (t == 63) *rowptrN = v;
}

__global__ __launch_bounds__(256)
void k_scan_fin(const int* __restrict__ deg, const int* __restrict__ part,
                int* __restrict__ rowptr, int* __restrict__ cursor, int N)
{
    int t = threadIdx.x, lane = t & 63, wave = t >> 6;
    int base = blockIdx.x * 2048 + t * 8;
    int vals[8]; int s = 0;
#pragma unroll
    for (int j = 0; j < 8; ++j) {
        int i = base + j;
        vals[j] = (i < N) ? deg[i] : 0;
        s += vals[j];
    }
    int inc = s;
#pragma unroll
    for (int off = 1; off < 64; off <<= 1) {
        int u = __shfl_up(inc, off, 64);
        if (lane >= off) inc += u;
    }
    __shared__ int wsum[4];
    if (lane == 63) wsum[wave] = inc;
    __syncthreads();
    int woff = 0;
#pragma unroll
    for (int w = 0; w < 4; ++w) if (w < wave) woff += wsum[w];
    int running = part[blockIdx.x] + woff + (inc - s);
#pragma unroll
    for (int j = 0; j < 8; ++j) {
        int i = base + j;
        if (i < N) { rowptr[i] = running; cursor[i] = running; }
        running += vals[j];
    }
}

// ---------------------------------------------------------------------------
// Scatter: place src id AND precomputed exp(leakyrelu(e)) per batch into
// dst-sorted order. One thread per edge — the exps are computed here, fully
// parallel, instead of redundantly by 64 lanes in the gather loop.
// ---------------------------------------------------------------------------
__global__ __launch_bounds__(256)
void k_scatter(const int* __restrict__ e_src, const int* __restrict__ e_dst,
               const float* __restrict__ s1, const float* __restrict__ s2,
               int* __restrict__ cursor, int* __restrict__ ssrc,
               float2* __restrict__ xs, int E, int N)
{
    int e = blockIdx.x * 256 + threadIdx.x;
    if (e >= E) return;
    int d = e_dst[e];
    int s = e_src[e];
    d = min(max(d, 0), N - 1);
    s = min(max(s, 0), N - 1);
    int p = atomicAdd(cursor + d, 1);
    float e0 = s1[s] + s2[d];
    float e1 = s1[N + s] + s2[N + d];
    e0 = e0 > 0.f ? e0 : ALPHA * e0;
    e1 = e1 > 0.f ? e1 : ALPHA * e1;
    ssrc[p] = s;
    xs[p] = make_float2(__expf(e0), __expf(e1));
}

// ---------------------------------------------------------------------------
// k_gather v2: one wave per dst. 4 edges per iteration: lane = (g = edge
// subgroup, q = feature quad); float4 Wh gathers; epilogue reduces over g
// via shfl_xor(16,32), then normalize + ELU + coalesced float4 store.
// ---------------------------------------------------------------------------
__global__ __launch_bounds__(256)
void k_gather(const int* __restrict__ rowptr, const int* __restrict__ ssrc,
              const float2* __restrict__ xs, const float* __restrict__ Wh,
              float* __restrict__ out, int N)
{
    int lane = threadIdx.x & 63;
    int d = blockIdx.x * 4 + (threadIdx.x >> 6);
    if (d >= N) return;
    int g = lane >> 4, q = lane & 15;

    int beg = rowptr[d];
    int end = rowptr[d + 1];
    const float4* Wh4 = (const float4*)Wh;

    float4 acc0 = make_float4(0.f, 0.f, 0.f, 0.f);
    float4 acc1 = make_float4(0.f, 0.f, 0.f, 0.f);
    float n0 = 0.f, n1 = 0.f;

    for (int i = beg; i < end; i += 4) {
        int e = i + g;
        bool valid = e < end;
        int ec = valid ? e : (end - 1);
        int s = ssrc[ec];
        float2 x = xs[ec];
        if (!valid) { x.x = 0.f; x.y = 0.f; }
        float4 w0 = Wh4[(size_t)s * 16 + q];
        float4 w1 = Wh4[((size_t)N + s) * 16 + q];
        acc0.x += x.x * w0.x; acc0.y += x.x * w0.y;
        acc0.z += x.x * w0.z; acc0.w += x.x * w0.w;
        acc1.x += x.y * w1.x; acc1.y += x.y * w1.y;
        acc1.z += x.y * w1.z; acc1.w += x.y * w1.w;
        n0 += x.x; n1 += x.y;
    }

#pragma unroll
    for (int off = 16; off <= 32; off <<= 1) {
        acc0.x += __shfl_xor(acc0.x, off, 64); acc0.y += __shfl_xor(acc0.y, off, 64);
        acc0.z += __shfl_xor(acc0.z, off, 64); acc0.w += __shfl_xor(acc0.w, off, 64);
        acc1.x += __shfl_xor(acc1.x, off, 64); acc1.y += __shfl_xor(acc1.y, off, 64);
        acc1.z += __shfl_xor(acc1.z, off, 64); acc1.w += __shfl_xor(acc1.w, off, 64);
        n0 += __shfl_xor(n0, off, 64); n1 += __shfl_xor(n1, off, 64);
    }

    float i0 = 1.f / (n0 + EPSV);
    float i1 = 1.f / (n1 + EPSV);
    float4 o0 = make_float4(acc0.x * i0, acc0.y * i0, acc0.z * i0, acc0.w * i0);
    float4 o1 = make_float4(acc1.x * i1, acc1.y * i1, acc1.z * i1, acc1.w * i1);
    o0.x = o0.x > 0.f ? o0.x : expm1f(o0.x); o0.y = o0.y > 0.f ? o0.y : expm1f(o0.y);
    o0.z = o0.z > 0.f ? o0.z : expm1f(o0.z); o0.w = o0.w > 0.f ? o0.w : expm1f(o0.w);
    o1.x = o1.x > 0.f ? o1.x : expm1f(o1.x); o1.y = o1.y > 0.f ? o1.y : expm1f(o1.y);
    o1.z = o1.z > 0.f ? o1.z : expm1f(o1.z); o1.w = o1.w > 0.f ? o1.w : expm1f(o1.w);

    if (g == 0) ((float4*)out)[(size_t)d * 16 + q] = o0;
    else if (g == 1) ((float4*)out)[((size_t)N + d) * 16 + q] = o1;
}

extern "C" void kernel_launch(void* const* d_in, const int* in_sizes, int n_in,
                              void* d_out, int out_size, void* d_ws, size_t ws_size,
                              hipStream_t stream)
{
    const float* h     = (const float*)d_in[0];
    const int*   ei    = (const int*)d_in[1];
    const float* Wfc   = (const float*)d_in[2];
    const float* Wattn = (const float*)d_in[3];
    float* out = (float*)d_out;

    int BN = in_sizes[0] / INF;     // B*N = 100000
    int N  = BN / 2;                // 50000
    int E  = in_sizes[1] / 2;       // 800000

    // ws: Wh[BN*64] | xs[E]f2 | s1[BN] | s2[BN] | deg[N] | rowptr[N+1] | cursor[N+1] | ssrc[E] | part[64]
    float*  Wh     = (float*)d_ws;
    float2* xs     = (float2*)(Wh + (size_t)BN * OUTF);
    float*  s1     = (float*)(xs + E);
    float*  s2     = s1 + BN;
    int*    deg    = (int*)(s2 + BN);
    int*    rowptr = deg + N;
    int*    cursor = rowptr + N + 1;
    int*    ssrc   = cursor + N + 1;
    int*    part   = ssrc + E;

    int nblk = (N + 2047) / 2048;   // 25 for N=50000 (<=64 supported)

    hipMemsetAsync(deg, 0, (size_t)N * sizeof(int), stream);

    k_fc<<<(BN / 16 + 3) / 4, 256, 0, stream>>>(h, Wfc, Wattn, Wh, s1, s2, BN);
    k_hist<<<(E + 255) / 256, 256, 0, stream>>>(ei + E, deg, E, N);
    k_scan_blk<<<nblk, 256, 0, stream>>>(deg, part, N);
    k_scan_mid<<<1, 64, 0, stream>>>(part, rowptr + N, nblk);
    k_scan_fin<<<nblk, 256, 0, stream>>>(deg, part, rowptr, cursor, N);
    k_scatter<<<(E + 255) / 256, 256, 0, stream>>>(ei, ei + E, s1, s2, cursor, ssrc, xs, E, N);
    k_gather<<<(N + 3) / 4, 256, 0, stream>>>(rowptr, ssrc, xs, Wh, out, N);
}